// Round 2
// baseline (415.067 us; speedup 1.0000x reference)
//
#include <hip/hip_runtime.h>

#define N_NODES 50000
#define N_EDGES 800000

// ---------------- Kernel 1: xgw[n, 0:192] = x @ g ; xgw[n, 192:256] = x @ root
__global__ void gemm_xw_kernel(const float* __restrict__ x,
                               const float* __restrict__ g,
                               const float* __restrict__ root,
                               float* __restrict__ xgw) {
    __shared__ float sW[64 * 256];
    __shared__ float sx[64];
    const int tid = threadIdx.x;
    for (int idx = tid; idx < 64 * 256; idx += 256) {
        int i = idx >> 8;
        int j = idx & 255;
        sW[idx] = (j < 192) ? g[i * 192 + j] : root[i * 64 + (j - 192)];
    }
    __syncthreads();
    for (int row = blockIdx.x; row < N_NODES; row += gridDim.x) {
        if (tid < 64) sx[tid] = x[(size_t)row * 64 + tid];
        __syncthreads();
        float acc = 0.f;
#pragma unroll
        for (int i = 0; i < 64; ++i)
            acc += sx[i] * sW[i * 256 + tid];
        xgw[(size_t)row * 256 + tid] = acc;
        __syncthreads();
    }
}

// ---------------- Kernel 2: histogram of destination degrees
__global__ void hist_kernel(const int* __restrict__ ei, int* __restrict__ counts) {
    int e = blockIdx.x * 256 + threadIdx.x;
    if (e < N_EDGES) atomicAdd(&counts[ei[N_EDGES + e]], 1);
}

// ---------------- Kernel 3: exclusive prefix scan (single block of 1024)
__global__ void scan_kernel(const int* __restrict__ counts,
                            int* __restrict__ off,
                            int* __restrict__ cursor) {
    __shared__ int sums[1024];
    const int T = 1024;
    const int tid = threadIdx.x;
    const int chunk = (N_NODES + T - 1) / T;  // 49
    const int base = tid * chunk;
    int local = 0;
    for (int i = 0; i < chunk; ++i) {
        int idx = base + i;
        if (idx < N_NODES) local += counts[idx];
    }
    sums[tid] = local;
    __syncthreads();
    // Hillis-Steele inclusive scan
    for (int d = 1; d < T; d <<= 1) {
        int v = (tid >= d) ? sums[tid - d] : 0;
        __syncthreads();
        sums[tid] += v;
        __syncthreads();
    }
    int run = (tid == 0) ? 0 : sums[tid - 1];
    for (int i = 0; i < chunk; ++i) {
        int idx = base + i;
        if (idx < N_NODES) {
            off[idx] = run;
            cursor[idx] = run;
            run += counts[idx];
        }
    }
    if (tid == T - 1) off[N_NODES] = run;
}

// ---------------- Kernel 4: compute weights, scatter packed edge records by dst
__global__ void scatter_kernel(const int* __restrict__ ei,
                               const float* __restrict__ pseudo,
                               const float* __restrict__ mu,
                               const float* __restrict__ sigma,
                               int* __restrict__ cursor,
                               float4* __restrict__ packed) {
    int e = blockIdx.x * 256 + threadIdx.x;
    if (e >= N_EDGES) return;
    const float mu0 = mu[0], mu1 = mu[1], mu2 = mu[2];
    const float s0 = sigma[0], s1 = sigma[1], s2 = sigma[2];
    const float c0 = -0.5f / (1e-14f + s0 * s0);
    const float c1 = -0.5f / (1e-14f + s1 * s1);
    const float c2 = -0.5f / (1e-14f + s2 * s2);
    const int s  = ei[e];
    const int dd = ei[N_EDGES + e];
    const float u = pseudo[e];
    const float d0 = u - mu0, d1 = u - mu1, d2 = u - mu2;
    const float w0 = expf(c0 * d0 * d0);
    const float w1 = expf(c1 * d1 * d1);
    const float w2 = expf(c2 * d2 * d2);
    const int pos = atomicAdd(&cursor[dd], 1);
    packed[pos] = make_float4(__int_as_float(s), w0, w1, w2);
}

// ---------------- Kernel 5: wave-per-node gather-accumulate + fused epilogue
__global__ void aggregate_kernel(const float* __restrict__ xgw,
                                 const float4* __restrict__ packed,
                                 const int* __restrict__ off,
                                 const float* __restrict__ x,
                                 const float* __restrict__ bias,
                                 float* __restrict__ out) {
    const int lane = threadIdx.x & 63;
    const int node = blockIdx.x * 4 + (threadIdx.x >> 6);
    if (node >= N_NODES) return;
    const int start = off[node], end = off[node + 1];
    float acc = 0.f;
    int j = start;
    for (; j + 1 < end; j += 2) {   // 2-edge unroll for memory-level parallelism
        const float4 p0 = packed[j];
        const float4 p1 = packed[j + 1];
        const float* b0 = xgw + (size_t)__float_as_int(p0.x) * 256;
        const float* b1 = xgw + (size_t)__float_as_int(p1.x) * 256;
        acc += p0.y * b0[lane] + p0.z * b0[64 + lane] + p0.w * b0[128 + lane];
        acc += p1.y * b1[lane] + p1.z * b1[64 + lane] + p1.w * b1[128 + lane];
    }
    if (j < end) {
        const float4 p = packed[j];
        const float* b = xgw + (size_t)__float_as_int(p.x) * 256;
        acc += p.y * b[lane] + p.z * b[64 + lane] + p.w * b[128 + lane];
    }
    const float cdeg = (float)(end - start);
    float v = acc / fmaxf(cdeg, 1.0f)
            + xgw[(size_t)node * 256 + 192 + lane]   // x @ root
            + bias[lane]
            + x[(size_t)node * 64 + lane];           // residual
    out[(size_t)node * 64 + lane] = v / (1.0f + expf(-v));  // silu
}

extern "C" void kernel_launch(void* const* d_in, const int* in_sizes, int n_in,
                              void* d_out, int out_size, void* d_ws, size_t ws_size,
                              hipStream_t stream) {
    const float* x     = (const float*)d_in[0];
    const int*   ei    = (const int*)d_in[1];
    const float* ea    = (const float*)d_in[2];
    const float* g     = (const float*)d_in[3];
    const float* mu    = (const float*)d_in[4];
    const float* sigma = (const float*)d_in[5];
    const float* root  = (const float*)d_in[6];
    const float* bias  = (const float*)d_in[7];
    float* out = (float*)d_out;

    char* ws = (char*)d_ws;
    const size_t xgw_bytes    = (size_t)N_NODES * 256 * sizeof(float);  // 51.2 MB
    const size_t packed_bytes = (size_t)N_EDGES * sizeof(float4);       // 12.8 MB
    float* xgw     = (float*)ws;
    float4* packed = (float4*)(ws + xgw_bytes);
    int* counts    = (int*)(ws + xgw_bytes + packed_bytes);
    int* off       = counts + N_NODES;          // N_NODES + 1 entries
    int* cursor    = off + N_NODES + 1;

    hipMemsetAsync(counts, 0, N_NODES * sizeof(int), stream);

    gemm_xw_kernel<<<2048, 256, 0, stream>>>(x, g, root, xgw);
    hist_kernel<<<(N_EDGES + 255) / 256, 256, 0, stream>>>(ei, counts);
    scan_kernel<<<1, 1024, 0, stream>>>(counts, off, cursor);
    scatter_kernel<<<(N_EDGES + 255) / 256, 256, 0, stream>>>(ei, ea, mu, sigma, cursor, packed);
    aggregate_kernel<<<(N_NODES + 3) / 4, 256, 0, stream>>>(xgw, packed, off, x, bias, out);
}